// Round 2
// baseline (3104.585 us; speedup 1.0000x reference)
//
#include <hip/hip_runtime.h>
#include <hip/hip_bf16.h>

typedef __attribute__((ext_vector_type(8))) short s8v;   // 8 bf16 (4 VGPRs) MFMA A/B frag
typedef __attribute__((ext_vector_type(4))) float f4v;   // MFMA C/D frag
typedef __attribute__((ext_vector_type(4))) short s4v;

__device__ __forceinline__ float b2f(short s) {
  unsigned int u = ((unsigned int)(unsigned short)s) << 16;
  return __builtin_bit_cast(float, u);
}
__device__ __forceinline__ short f2b(float f) {
  __hip_bfloat16 h = __float2bfloat16(f);  // RNE
  return __builtin_bit_cast(short, h);
}

__device__ __forceinline__ void gload_lds16(const short* g, short* l) {
  __builtin_amdgcn_global_load_lds(
      (const __attribute__((address_space(1))) unsigned int*)g,
      (__attribute__((address_space(3))) unsigned int*)l, 16, 0, 0);
}

// ---------------------------------------------------------------------------
// fp32 -> bf16 weight conversion (per-launch; graph-capture-safe)
// ---------------------------------------------------------------------------
__global__ __launch_bounds__(256)
void cvt_f32_bf16(const float* __restrict__ in, short* __restrict__ out, int n) {
  int i = (blockIdx.x * 256 + threadIdx.x) * 4;
  if (i < n) {
    float4 v = *(const float4*)(in + i);
    s4v o = {f2b(v.x), f2b(v.y), f2b(v.z), f2b(v.w)};
    *(s4v*)(out + i) = o;
  }
}

// ---------------------------------------------------------------------------
// BT GEMM: C[M,N] = A[M,K](bf16) @ B[N,K]^T(bf16) + bias(f32) (+res f32)
// (relu?) -> outf f32 and/or outb bf16.  128x128 tile, BK=64, 256 thr.
// res/outf may alias elementwise (in-place residual) -> no __restrict__.
// ---------------------------------------------------------------------------
__global__ __launch_bounds__(256, 2)
void gemm_bt(const short* __restrict__ A, const short* __restrict__ B,
             const float* __restrict__ bias, const float* res,
             float* outf, short* outb,
             int M, int N, int K, int ldc, int relu) {
  __shared__ short As[128 * 64];
  __shared__ short Bs[128 * 64];
  const int tid  = threadIdx.x;
  const int lane = tid & 63;
  const int w    = tid >> 6;
  const int wm   = w >> 1, wn = w & 1;
  const int llo  = lane & 15, g = lane >> 4;
  const int bm   = blockIdx.x, bn = blockIdx.y;

  const int srow = w * 32 + (lane >> 3);   // staging row within tile (+t*8)
  const int scol = (lane & 7) * 8;         // staging col (elems)

  f4v acc[4][4];
#pragma unroll
  for (int i = 0; i < 4; ++i)
#pragma unroll
    for (int j = 0; j < 4; ++j) acc[i][j] = (f4v){0.f, 0.f, 0.f, 0.f};

  for (int k0 = 0; k0 < K; k0 += 64) {
    __syncthreads();
#pragma unroll
    for (int t = 0; t < 4; ++t) {
      int ar = bm * 128 + srow + t * 8;                       // M % 128 == 0
      int br = bn * 128 + srow + t * 8; if (br >= N) br = N - 1;
      gload_lds16(A + (size_t)ar * K + k0 + scol, As + (w * 32 + t * 8) * 64);
      gload_lds16(B + (size_t)br * K + k0 + scol, Bs + (w * 32 + t * 8) * 64);
    }
    __syncthreads();
#pragma unroll
    for (int ks = 0; ks < 2; ++ks) {
      s8v a[4], b[4];
#pragma unroll
      for (int mi = 0; mi < 4; ++mi)
        a[mi] = *(const s8v*)&As[(wm * 64 + mi * 16 + llo) * 64 + ks * 32 + g * 8];
#pragma unroll
      for (int ni = 0; ni < 4; ++ni)
        b[ni] = *(const s8v*)&Bs[(wn * 64 + ni * 16 + llo) * 64 + ks * 32 + g * 8];
#pragma unroll
      for (int mi = 0; mi < 4; ++mi)
#pragma unroll
        for (int ni = 0; ni < 4; ++ni)
          acc[mi][ni] = __builtin_amdgcn_mfma_f32_16x16x32_bf16(a[mi], b[ni], acc[mi][ni], 0, 0, 0);
    }
  }

  const int r0 = bm * 128 + wm * 64;
  const int c0 = bn * 128 + wn * 64 + llo;
#pragma unroll
  for (int mi = 0; mi < 4; ++mi) {
#pragma unroll
    for (int ni = 0; ni < 4; ++ni) {
      int col = c0 + ni * 16;
      if (col < N) {
        float bv = bias ? bias[col] : 0.f;
#pragma unroll
        for (int r = 0; r < 4; ++r) {
          int row = r0 + mi * 16 + g * 4 + r;   // C/D: col=lane&15, row=(lane>>4)*4+reg
          float v = acc[mi][ni][r] + bv;
          if (res)  v += res[(size_t)row * ldc + col];
          if (relu) v = fmaxf(v, 0.f);
          if (outf) outf[(size_t)row * ldc + col] = v;
          if (outb) outb[(size_t)row * ldc + col] = f2b(v);
        }
      }
    }
  }
}

// ---------------------------------------------------------------------------
// Flash attention, one block per (b, head, 128-row Q tile). Causal.
// qkv: [4096, 3072] bf16 (q|k|v per token). att: [4096, 1024] bf16.
// ---------------------------------------------------------------------------
#define ALD 136   // padded LDS row stride (elems)

__global__ __launch_bounds__(256, 1)
void attn_kernel(const short* __restrict__ qkv, short* __restrict__ att) {
  __shared__ short Qs[128 * ALD];
  __shared__ short Ks[128 * ALD];
  __shared__ short Vt[128 * ALD];   // transposed: Vt[d][s]
  __shared__ short Ps[128 * ALD];
  const int tid = threadIdx.x;
  const int lane = tid & 63, w = tid >> 6;
  const int llo = lane & 15, g = lane >> 4;
  const int qt = blockIdx.x, hh = blockIdx.y, b = blockIdx.z;
  const float scale = 0.08838834764831845f;   // 1/sqrt(128)

  const short* qbase = qkv + (size_t)(b * 1024 + qt * 128) * 3072 + hh * 128;
#pragma unroll
  for (int pass = 0; pass < 8; ++pass) {
    int chunk = pass * 256 + tid;
    int rr = chunk >> 4, c8 = (chunk & 15) * 8;
    *(s8v*)&Qs[rr * ALD + c8] = *(const s8v*)&qbase[(size_t)rr * 3072 + c8];
  }

  f4v o[2][8];
#pragma unroll
  for (int mi = 0; mi < 2; ++mi)
#pragma unroll
    for (int ni = 0; ni < 8; ++ni) o[mi][ni] = (f4v){0.f, 0.f, 0.f, 0.f};
  float m_i[2][4], l_i[2][4];
#pragma unroll
  for (int mi = 0; mi < 2; ++mi)
#pragma unroll
    for (int r = 0; r < 4; ++r) { m_i[mi][r] = -1e30f; l_i[mi][r] = 0.f; }

  for (int kt = 0; kt <= qt; ++kt) {
    __syncthreads();   // prior PV reads of Ks/Vt done
    const short* kbase = qkv + (size_t)(b * 1024 + kt * 128) * 3072 + 1024 + hh * 128;
    const short* vbase = qkv + (size_t)(b * 1024 + kt * 128) * 3072 + 2048 + hh * 128;
#pragma unroll
    for (int pass = 0; pass < 8; ++pass) {
      int chunk = pass * 256 + tid;
      int rr = chunk >> 4, c8 = (chunk & 15) * 8;
      *(s8v*)&Ks[rr * ALD + c8] = *(const s8v*)&kbase[(size_t)rr * 3072 + c8];
      int s = chunk & 127, d0 = (chunk >> 7) * 8;
      s8v vv = *(const s8v*)&vbase[(size_t)s * 3072 + d0];
#pragma unroll
      for (int j = 0; j < 8; ++j) Vt[(d0 + j) * ALD + s] = vv[j];
    }
    __syncthreads();

    // S = Q K^T
    f4v sc[2][8];
#pragma unroll
    for (int mi = 0; mi < 2; ++mi)
#pragma unroll
      for (int ni = 0; ni < 8; ++ni) sc[mi][ni] = (f4v){0.f, 0.f, 0.f, 0.f};
#pragma unroll
    for (int ks = 0; ks < 4; ++ks) {
      s8v aq0 = *(const s8v*)&Qs[(w * 32 + llo) * ALD + ks * 32 + g * 8];
      s8v aq1 = *(const s8v*)&Qs[(w * 32 + 16 + llo) * ALD + ks * 32 + g * 8];
#pragma unroll
      for (int ni = 0; ni < 8; ++ni) {
        s8v bk = *(const s8v*)&Ks[(ni * 16 + llo) * ALD + ks * 32 + g * 8];
        sc[0][ni] = __builtin_amdgcn_mfma_f32_16x16x32_bf16(aq0, bk, sc[0][ni], 0, 0, 0);
        sc[1][ni] = __builtin_amdgcn_mfma_f32_16x16x32_bf16(aq1, bk, sc[1][ni], 0, 0, 0);
      }
    }

    const bool diag = (kt == qt);
#pragma unroll
    for (int mi = 0; mi < 2; ++mi) {
#pragma unroll
      for (int r = 0; r < 4; ++r) {
        int row_local = w * 32 + mi * 16 + g * 4 + r;
        float mx = -1e30f;
#pragma unroll
        for (int ni = 0; ni < 8; ++ni) {
          float v = sc[mi][ni][r] * scale;
          if (diag && (ni * 16 + llo) > row_local) v = -1e30f;
          sc[mi][ni][r] = v;
          mx = fmaxf(mx, v);
        }
        mx = fmaxf(mx, __shfl_xor(mx, 1, 64));
        mx = fmaxf(mx, __shfl_xor(mx, 2, 64));
        mx = fmaxf(mx, __shfl_xor(mx, 4, 64));
        mx = fmaxf(mx, __shfl_xor(mx, 8, 64));
        float mnew  = fmaxf(m_i[mi][r], mx);
        float alpha = __expf(m_i[mi][r] - mnew);
        m_i[mi][r]  = mnew;
        float rs = 0.f;
#pragma unroll
        for (int ni = 0; ni < 8; ++ni) {
          float p = __expf(sc[mi][ni][r] - mnew);
          rs += p;
          Ps[row_local * ALD + ni * 16 + llo] = f2b(p);
        }
        rs += __shfl_xor(rs, 1, 64);
        rs += __shfl_xor(rs, 2, 64);
        rs += __shfl_xor(rs, 4, 64);
        rs += __shfl_xor(rs, 8, 64);
        l_i[mi][r] = l_i[mi][r] * alpha + rs;
#pragma unroll
        for (int ni = 0; ni < 8; ++ni) o[mi][ni][r] *= alpha;
      }
    }
    __syncthreads();   // Ps ready

    // O += P V
#pragma unroll
    for (int ks = 0; ks < 4; ++ks) {
      s8v ap0 = *(const s8v*)&Ps[(w * 32 + llo) * ALD + ks * 32 + g * 8];
      s8v ap1 = *(const s8v*)&Ps[(w * 32 + 16 + llo) * ALD + ks * 32 + g * 8];
#pragma unroll
      for (int ni = 0; ni < 8; ++ni) {
        s8v bv = *(const s8v*)&Vt[(ni * 16 + llo) * ALD + ks * 32 + g * 8];
        o[0][ni] = __builtin_amdgcn_mfma_f32_16x16x32_bf16(ap0, bv, o[0][ni], 0, 0, 0);
        o[1][ni] = __builtin_amdgcn_mfma_f32_16x16x32_bf16(ap1, bv, o[1][ni], 0, 0, 0);
      }
    }
  }

#pragma unroll
  for (int mi = 0; mi < 2; ++mi)
#pragma unroll
    for (int r = 0; r < 4; ++r) {
      float inv = 1.f / l_i[mi][r];
      int row_local = w * 32 + mi * 16 + g * 4 + r;
      size_t obase = (size_t)(b * 1024 + qt * 128 + row_local) * 1024 + hh * 128;
#pragma unroll
      for (int ni = 0; ni < 8; ++ni)
        att[obase + ni * 16 + llo] = f2b(o[mi][ni][r] * inv);
    }
}

// ---------------------------------------------------------------------------
// LayerNorm over D=1024: in f32 -> outf f32 (optional, may alias in) + outb bf16
// ---------------------------------------------------------------------------
__global__ __launch_bounds__(256)
void ln_kernel(const float* in, const float* __restrict__ gw,
               const float* __restrict__ bw, float* outf,
               short* __restrict__ outb) {
  const int row = blockIdx.x, tid = threadIdx.x;
  const int lane = tid & 63, w = tid >> 6;
  float4 v = *(const float4*)(in + (size_t)row * 1024 + tid * 4);
  float s = v.x + v.y + v.z + v.w;
  float q = v.x * v.x + v.y * v.y + v.z * v.z + v.w * v.w;
  for (int off = 1; off < 64; off <<= 1) {
    s += __shfl_xor(s, off, 64);
    q += __shfl_xor(q, off, 64);
  }
  __shared__ float red[8];
  if (lane == 0) { red[w] = s; red[4 + w] = q; }
  __syncthreads();
  s = red[0] + red[1] + red[2] + red[3];
  q = red[4] + red[5] + red[6] + red[7];
  const float mean = s * (1.0f / 1024.0f);
  const float var  = q * (1.0f / 1024.0f) - mean * mean;
  const float rstd = rsqrtf(var + 1e-5f);
  const int d = tid * 4;
  float4 gv = *(const float4*)(gw + d);
  float4 bv = *(const float4*)(bw + d);
  float o0 = (v.x - mean) * rstd * gv.x + bv.x;
  float o1 = (v.y - mean) * rstd * gv.y + bv.y;
  float o2 = (v.z - mean) * rstd * gv.z + bv.z;
  float o3 = (v.w - mean) * rstd * gv.w + bv.w;
  if (outf) {
    float4 ov = {o0, o1, o2, o3};
    *(float4*)(outf + (size_t)row * 1024 + d) = ov;
  }
  s4v ob = {f2b(o0), f2b(o1), f2b(o2), f2b(o3)};
  *(s4v*)(outb + (size_t)row * 1024 + d) = ob;
}

// ---------------------------------------------------------------------------
// Patch embedding: h[m,d] = sum_p x[m*96+p] * Wemb[d,p] + PE(m%1024, d)
// x fp32, Wemb_b bf16 (pre-converted). 16 tokens/block, 256 threads.
// ---------------------------------------------------------------------------
__global__ __launch_bounds__(256)
void embed_kernel(const float* __restrict__ x, const short* __restrict__ Wemb,
                  float* __restrict__ hf, short* __restrict__ hb) {
  __shared__ float Xs[16 * 96];
  const int tid = threadIdx.x;
  const int m0  = blockIdx.x * 16;
  for (int i = tid; i < 16 * 96; i += 256) Xs[i] = x[(size_t)m0 * 96 + i];
  __syncthreads();

  const int d0 = tid * 4;
  float acc[4][16];
#pragma unroll
  for (int j = 0; j < 4; ++j)
#pragma unroll
    for (int t = 0; t < 16; ++t) acc[j][t] = 0.f;

  for (int pc = 0; pc < 12; ++pc) {
    float wf[4][8];
#pragma unroll
    for (int j = 0; j < 4; ++j) {
      s8v wv = *(const s8v*)&Wemb[(size_t)(d0 + j) * 96 + pc * 8];
#pragma unroll
      for (int u = 0; u < 8; ++u) wf[j][u] = b2f(wv[u]);
    }
#pragma unroll
    for (int t = 0; t < 16; ++t) {
      float4 xa = *(const float4*)&Xs[t * 96 + pc * 8];
      float4 xb = *(const float4*)&Xs[t * 96 + pc * 8 + 4];
      float xv[8] = {xa.x, xa.y, xa.z, xa.w, xb.x, xb.y, xb.z, xb.w};
#pragma unroll
      for (int u = 0; u < 8; ++u)
#pragma unroll
        for (int j = 0; j < 4; ++j) acc[j][t] += xv[u] * wf[j][u];
    }
  }

#pragma unroll
  for (int j = 0; j < 4; ++j) {
    int d = d0 + j;
    float freq = __expf((float)(d & ~1) * (-0.008994473019508041f)); // -ln(1e4)/1024
#pragma unroll
    for (int t = 0; t < 16; ++t) {
      int n = (m0 + t) & 1023;
      float arg = (float)n * freq;
      float pe  = (d & 1) ? cosf(arg) : sinf(arg);
      float val = acc[j][t] + pe;
      hf[(size_t)(m0 + t) * 1024 + d] = val;
      hb[(size_t)(m0 + t) * 1024 + d] = f2b(val);
    }
  }
}

// ---------------------------------------------------------------------------
extern "C" void kernel_launch(void* const* d_in, const int* in_sizes, int n_in,
                              void* d_out, int out_size, void* d_ws, size_t ws_size,
                              hipStream_t stream) {
  (void)in_sizes; (void)n_in; (void)out_size; (void)ws_size;
  const float* x    = (const float*)d_in[0];
  const float* Wemb = (const float*)d_in[1];
  const float* Wq   = (const float*)d_in[2];
  const float* bq   = (const float*)d_in[3];
  const float* Wk   = (const float*)d_in[4];
  const float* bk   = (const float*)d_in[5];
  const float* Wv   = (const float*)d_in[6];
  const float* bv   = (const float*)d_in[7];
  const float* Wo   = (const float*)d_in[8];
  const float* bo   = (const float*)d_in[9];
  const float* Wc1  = (const float*)d_in[10];
  const float* bc1  = (const float*)d_in[11];
  const float* Wc2  = (const float*)d_in[12];
  const float* bc2  = (const float*)d_in[13];
  const float* g1   = (const float*)d_in[14];
  const float* be1  = (const float*)d_in[15];
  const float* g2   = (const float*)d_in[16];
  const float* be2  = (const float*)d_in[17];
  const float* gN   = (const float*)d_in[18];
  const float* beN  = (const float*)d_in[19];
  const float* Wp   = (const float*)d_in[20];
  const float* bp   = (const float*)d_in[21];

  char* wsc = (char*)d_ws;
  const size_t MB = 1024 * 1024;
  // bf16 weight mirror: 0..~128.4 MB
  short* wq_b   = (short*)(wsc + 0 * MB);      // 16 MB (8 layers x 1M elems)
  short* wk_b   = (short*)(wsc + 16 * MB);
  short* wv_b   = (short*)(wsc + 32 * MB);
  short* wo_b   = (short*)(wsc + 48 * MB);
  short* wc1_b  = (short*)(wsc + 64 * MB);     // 32 MB
  short* wc2_b  = (short*)(wsc + 96 * MB);     // 32 MB
  short* wemb_b = (short*)(wsc + 128 * MB);    // 192 KB
  short* wp_b   = (short*)(wsc + 128 * MB + 196608);  // 192 KB
  float* h_f32  = (float*)(wsc + 132 * MB);    // 16 MB fp32 residual trunk
  short* h_bf   = (short*)(wsc + 148 * MB);    //  8 MB bf16 A-operand copy
  short* qkv    = (short*)(wsc + 156 * MB);    // 24 MB [4096,3072]; aliased as y1
  short* att    = (short*)(wsc + 180 * MB);    //  8 MB [4096,1024]
  short* y1     = qkv;                         // FFN mid [4096,2048]

  // fp32 -> bf16 weight conversion
  cvt_f32_bf16<<<8192, 256, 0, stream>>>(Wq, wq_b, 8 * 1024 * 1024);
  cvt_f32_bf16<<<8192, 256, 0, stream>>>(Wk, wk_b, 8 * 1024 * 1024);
  cvt_f32_bf16<<<8192, 256, 0, stream>>>(Wv, wv_b, 8 * 1024 * 1024);
  cvt_f32_bf16<<<8192, 256, 0, stream>>>(Wo, wo_b, 8 * 1024 * 1024);
  cvt_f32_bf16<<<16384, 256, 0, stream>>>(Wc1, wc1_b, 16 * 1024 * 1024);
  cvt_f32_bf16<<<16384, 256, 0, stream>>>(Wc2, wc2_b, 16 * 1024 * 1024);
  cvt_f32_bf16<<<96, 256, 0, stream>>>(Wemb, wemb_b, 98304);
  cvt_f32_bf16<<<96, 256, 0, stream>>>(Wp, wp_b, 98304);

  embed_kernel<<<256, 256, 0, stream>>>(x, wemb_b, h_f32, h_bf);

  for (int i = 0; i < 8; ++i) {
    const short* wq = wq_b + (size_t)i * 1024 * 1024;
    const short* wk = wk_b + (size_t)i * 1024 * 1024;
    const short* wv = wv_b + (size_t)i * 1024 * 1024;
    const short* wo = wo_b + (size_t)i * 1024 * 1024;
    const short* w1 = wc1_b + (size_t)i * 2048 * 1024;
    const short* w2 = wc2_b + (size_t)i * 1024 * 2048;

    gemm_bt<<<dim3(32, 8), 256, 0, stream>>>(h_bf, wq, bq + i * 1024, nullptr,
                                             nullptr, qkv + 0,    4096, 1024, 1024, 3072, 0);
    gemm_bt<<<dim3(32, 8), 256, 0, stream>>>(h_bf, wk, bk + i * 1024, nullptr,
                                             nullptr, qkv + 1024, 4096, 1024, 1024, 3072, 0);
    gemm_bt<<<dim3(32, 8), 256, 0, stream>>>(h_bf, wv, bv + i * 1024, nullptr,
                                             nullptr, qkv + 2048, 4096, 1024, 1024, 3072, 0);
    attn_kernel<<<dim3(8, 8, 4), 256, 0, stream>>>(qkv, att);
    // h += att @ Wo^T + bo   (in-place residual on fp32 trunk)
    gemm_bt<<<dim3(32, 8), 256, 0, stream>>>(att, wo, bo + i * 1024, h_f32,
                                             h_f32, nullptr, 4096, 1024, 1024, 1024, 0);
    ln_kernel<<<4096, 256, 0, stream>>>(h_f32, g1 + i * 1024, be1 + i * 1024, h_f32, h_bf);
    gemm_bt<<<dim3(32, 16), 256, 0, stream>>>(h_bf, w1, bc1 + i * 2048, nullptr,
                                              nullptr, y1, 4096, 2048, 1024, 2048, 1);
    gemm_bt<<<dim3(32, 8), 256, 0, stream>>>(y1, w2, bc2 + i * 1024, h_f32,
                                             h_f32, nullptr, 4096, 1024, 2048, 1024, 0);
    ln_kernel<<<4096, 256, 0, stream>>>(h_f32, g2 + i * 1024, be2 + i * 1024, h_f32, h_bf);
  }

  ln_kernel<<<4096, 256, 0, stream>>>(h_f32, gN, beN, nullptr, h_bf);
  gemm_bt<<<dim3(32, 1), 256, 0, stream>>>(h_bf, wp_b, bp, nullptr,
                                           (float*)d_out, nullptr, 4096, 96, 1024, 96, 0);
}

// Round 3
// 2229.591 us; speedup vs baseline: 1.3924x; 1.3924x over previous
//
#include <hip/hip_runtime.h>
#include <hip/hip_bf16.h>

typedef __attribute__((ext_vector_type(8))) short s8v;   // 8 bf16 (4 VGPRs) MFMA A/B frag
typedef __attribute__((ext_vector_type(4))) float f4v;   // MFMA C/D frag
typedef __attribute__((ext_vector_type(4))) short s4v;

__device__ __forceinline__ float b2f(short s) {
  unsigned int u = ((unsigned int)(unsigned short)s) << 16;
  return __builtin_bit_cast(float, u);
}
__device__ __forceinline__ short f2b(float f) {
  __hip_bfloat16 h = __float2bfloat16(f);  // RNE
  return __builtin_bit_cast(short, h);
}

__device__ __forceinline__ void gload_lds16(const short* g, short* l) {
  __builtin_amdgcn_global_load_lds(
      (const __attribute__((address_space(1))) unsigned int*)g,
      (__attribute__((address_space(3))) unsigned int*)l, 16, 0, 0);
}

// ---------------------------------------------------------------------------
// fp32 -> bf16 conversion kernels (per-launch; graph-capture-safe)
// ---------------------------------------------------------------------------
__global__ __launch_bounds__(256)
void cvt_f32_bf16(const float* __restrict__ in, short* __restrict__ out, int n) {
  int i = (blockIdx.x * 256 + threadIdx.x) * 4;
  if (i < n) {
    float4 v = *(const float4*)(in + i);
    s4v o = {f2b(v.x), f2b(v.y), f2b(v.z), f2b(v.w)};
    *(s4v*)(out + i) = o;
  }
}

// pack Wq/Wk/Wv [8][1024][1024] f32 into fused [8][3072][1024] bf16 at base_off rows
__global__ __launch_bounds__(256)
void cvt_pack_w(const float* __restrict__ in, short* __restrict__ out, int base_off) {
  int i = (blockIdx.x * 256 + threadIdx.x) * 4;
  if (i < 8 * 1048576) {
    int layer = i >> 20, rem = i & 1048575;
    float4 v = *(const float4*)(in + i);
    s4v o = {f2b(v.x), f2b(v.y), f2b(v.z), f2b(v.w)};
    *(s4v*)(out + (size_t)layer * 3145728 + (size_t)base_off * 1024 + rem) = o;
  }
}

// pack bq/bk/bv [8][1024] f32 into fused [8][3072] f32
__global__ __launch_bounds__(256)
void pack_bias(const float* __restrict__ in, float* __restrict__ out, int off) {
  int i = blockIdx.x * 256 + threadIdx.x;
  if (i < 8192) {
    int layer = i >> 10, rem = i & 1023;
    out[layer * 3072 + off + rem] = in[i];
  }
}

// ---------------------------------------------------------------------------
// BT GEMM 128x128 tile: C[M,N] = A[M,K](bf16) @ B[N,K]^T(bf16) + bias(f32)
// (+res f32)(relu?) -> outf f32 and/or outb bf16.  BK=64, 256 thr, 4 waves 2x2.
// ---------------------------------------------------------------------------
__global__ __launch_bounds__(256, 2)
void gemm_bt(const short* __restrict__ A, const short* __restrict__ B,
             const float* __restrict__ bias, const float* res,
             float* outf, short* outb,
             int M, int N, int K, int ldc, int relu) {
  __shared__ short As[128 * 64];
  __shared__ short Bs[128 * 64];
  const int tid  = threadIdx.x;
  const int lane = tid & 63;
  const int w    = tid >> 6;
  const int wm   = w >> 1, wn = w & 1;
  const int llo  = lane & 15, g = lane >> 4;
  const int bm   = blockIdx.x, bn = blockIdx.y;

  const int srow = w * 32 + (lane >> 3);   // staging row within tile (+t*8)
  const int scol = (lane & 7) * 8;         // staging col (elems)

  f4v acc[4][4];
#pragma unroll
  for (int i = 0; i < 4; ++i)
#pragma unroll
    for (int j = 0; j < 4; ++j) acc[i][j] = (f4v){0.f, 0.f, 0.f, 0.f};

  for (int k0 = 0; k0 < K; k0 += 64) {
    __syncthreads();
#pragma unroll
    for (int t = 0; t < 4; ++t) {
      int ar = bm * 128 + srow + t * 8;                       // M % 128 == 0
      int br = bn * 128 + srow + t * 8; if (br >= N) br = N - 1;
      gload_lds16(A + (size_t)ar * K + k0 + scol, As + (w * 32 + t * 8) * 64);
      gload_lds16(B + (size_t)br * K + k0 + scol, Bs + (w * 32 + t * 8) * 64);
    }
    __syncthreads();
#pragma unroll
    for (int ks = 0; ks < 2; ++ks) {
      s8v a[4], b[4];
#pragma unroll
      for (int mi = 0; mi < 4; ++mi)
        a[mi] = *(const s8v*)&As[(wm * 64 + mi * 16 + llo) * 64 + ks * 32 + g * 8];
#pragma unroll
      for (int ni = 0; ni < 4; ++ni)
        b[ni] = *(const s8v*)&Bs[(wn * 64 + ni * 16 + llo) * 64 + ks * 32 + g * 8];
#pragma unroll
      for (int mi = 0; mi < 4; ++mi)
#pragma unroll
        for (int ni = 0; ni < 4; ++ni)
          acc[mi][ni] = __builtin_amdgcn_mfma_f32_16x16x32_bf16(a[mi], b[ni], acc[mi][ni], 0, 0, 0);
    }
  }

  const int r0 = bm * 128 + wm * 64;
  const int c0 = bn * 128 + wn * 64 + llo;
#pragma unroll
  for (int mi = 0; mi < 4; ++mi) {
#pragma unroll
    for (int ni = 0; ni < 4; ++ni) {
      int col = c0 + ni * 16;
      if (col < N) {
        float bv = bias ? bias[col] : 0.f;
#pragma unroll
        for (int r = 0; r < 4; ++r) {
          int row = r0 + mi * 16 + g * 4 + r;   // C/D: col=lane&15, row=(lane>>4)*4+reg
          float v = acc[mi][ni][r] + bv;
          if (res)  v += res[(size_t)row * ldc + col];
          if (relu) v = fmaxf(v, 0.f);
          if (outf) outf[(size_t)row * ldc + col] = v;
          if (outb) outb[(size_t)row * ldc + col] = f2b(v);
        }
      }
    }
  }
}

// ---------------------------------------------------------------------------
// BT GEMM 64x128 tile (for 256-block shapes -> 512 blocks, 2 blocks/CU).
// 256 thr, 4 waves in 1x4 (each wave: all 64 M rows x 32 cols).
// ---------------------------------------------------------------------------
__global__ __launch_bounds__(256, 2)
void gemm_bt64(const short* __restrict__ A, const short* __restrict__ B,
               const float* __restrict__ bias, const float* res,
               float* outf, short* outb,
               int M, int N, int K, int ldc, int relu) {
  __shared__ short As[64 * 64];
  __shared__ short Bs[128 * 64];
  const int tid  = threadIdx.x;
  const int lane = tid & 63;
  const int w    = tid >> 6;
  const int llo  = lane & 15, g = lane >> 4;
  const int bm   = blockIdx.x, bn = blockIdx.y;
  const int sr   = lane >> 3;
  const int scol = (lane & 7) * 8;

  f4v acc[4][2];
#pragma unroll
  for (int i = 0; i < 4; ++i)
#pragma unroll
    for (int j = 0; j < 2; ++j) acc[i][j] = (f4v){0.f, 0.f, 0.f, 0.f};

  for (int k0 = 0; k0 < K; k0 += 64) {
    __syncthreads();
#pragma unroll
    for (int t = 0; t < 2; ++t) {
      int ar = bm * 64 + w * 16 + t * 8 + sr;                 // M % 64 == 0
      gload_lds16(A + (size_t)ar * K + k0 + scol, As + (w * 16 + t * 8) * 64);
    }
#pragma unroll
    for (int t = 0; t < 4; ++t) {
      int br = bn * 128 + w * 32 + t * 8 + sr; if (br >= N) br = N - 1;
      gload_lds16(B + (size_t)br * K + k0 + scol, Bs + (w * 32 + t * 8) * 64);
    }
    __syncthreads();
#pragma unroll
    for (int ks = 0; ks < 2; ++ks) {
      s8v a[4], b[2];
#pragma unroll
      for (int mi = 0; mi < 4; ++mi)
        a[mi] = *(const s8v*)&As[(mi * 16 + llo) * 64 + ks * 32 + g * 8];
#pragma unroll
      for (int ni = 0; ni < 2; ++ni)
        b[ni] = *(const s8v*)&Bs[(w * 32 + ni * 16 + llo) * 64 + ks * 32 + g * 8];
#pragma unroll
      for (int mi = 0; mi < 4; ++mi)
#pragma unroll
        for (int ni = 0; ni < 2; ++ni)
          acc[mi][ni] = __builtin_amdgcn_mfma_f32_16x16x32_bf16(a[mi], b[ni], acc[mi][ni], 0, 0, 0);
    }
  }

  const int r0 = bm * 64;
  const int c0 = bn * 128 + w * 32 + llo;
#pragma unroll
  for (int mi = 0; mi < 4; ++mi) {
#pragma unroll
    for (int ni = 0; ni < 2; ++ni) {
      int col = c0 + ni * 16;
      if (col < N) {
        float bv = bias ? bias[col] : 0.f;
#pragma unroll
        for (int r = 0; r < 4; ++r) {
          int row = r0 + mi * 16 + g * 4 + r;
          float v = acc[mi][ni][r] + bv;
          if (res)  v += res[(size_t)row * ldc + col];
          if (relu) v = fmaxf(v, 0.f);
          if (outf) outf[(size_t)row * ldc + col] = v;
          if (outb) outb[(size_t)row * ldc + col] = f2b(v);
        }
      }
    }
  }
}

// ---------------------------------------------------------------------------
// Flash attention: block = (b, head, 128-row Q tile), 512 thr = 8 waves.
// Each wave owns a private 16-row Q strip (Q in registers); softmax + P
// round-trip are wave-local (no block barrier). K/V staged per kt tile.
// qkv: [4096, 3072] bf16 (q|k|v per token). att: [4096, 1024] bf16.
// ---------------------------------------------------------------------------
#define ALD 136   // padded LDS row stride (elems)

__global__ __launch_bounds__(512, 1)
void attn_kernel(const short* __restrict__ qkv, short* __restrict__ att) {
  __shared__ short Ks[128 * ALD];
  __shared__ short Vt[128 * ALD];   // transposed: Vt[d][s]
  __shared__ short Ps[128 * ALD];
  const int tid = threadIdx.x;
  const int lane = tid & 63, w = tid >> 6;
  const int llo = lane & 15, g = lane >> 4;
  const int qt = blockIdx.x, hh = blockIdx.y, b = blockIdx.z;
  const float scale = 0.08838834764831845f;   // 1/sqrt(128)

  // Q strip (rows w*16..w*16+15) into A-frag registers
  s8v qreg[4];
  {
    const short* qrow = qkv + (size_t)(b * 1024 + qt * 128 + w * 16 + llo) * 3072 + hh * 128;
#pragma unroll
    for (int ks = 0; ks < 4; ++ks) qreg[ks] = *(const s8v*)&qrow[ks * 32 + g * 8];
  }

  f4v o[8];
#pragma unroll
  for (int ni = 0; ni < 8; ++ni) o[ni] = (f4v){0.f, 0.f, 0.f, 0.f};
  float m_i[4], l_i[4];
#pragma unroll
  for (int r = 0; r < 4; ++r) { m_i[r] = -1e30f; l_i[r] = 0.f; }

  for (int kt = 0; kt <= qt; ++kt) {
    __syncthreads();   // prior PV reads of Ks/Vt done (all waves)
    const short* kbase = qkv + (size_t)(b * 1024 + kt * 128) * 3072 + 1024 + hh * 128;
    const short* vbase = qkv + (size_t)(b * 1024 + kt * 128) * 3072 + 2048 + hh * 128;
#pragma unroll
    for (int pass = 0; pass < 4; ++pass) {
      int chunk = pass * 512 + tid;
      int rr = chunk >> 4, c8 = (chunk & 15) * 8;
      *(s8v*)&Ks[rr * ALD + c8] = *(const s8v*)&kbase[(size_t)rr * 3072 + c8];
      int s = chunk & 127, d0 = (chunk >> 7) * 8;
      s8v vv = *(const s8v*)&vbase[(size_t)s * 3072 + d0];
#pragma unroll
      for (int j = 0; j < 8; ++j) Vt[(d0 + j) * ALD + s] = vv[j];
    }
    __syncthreads();

    // S = Q K^T for this wave's 16-row strip
    f4v sc[8];
#pragma unroll
    for (int ni = 0; ni < 8; ++ni) sc[ni] = (f4v){0.f, 0.f, 0.f, 0.f};
#pragma unroll
    for (int ks = 0; ks < 4; ++ks) {
#pragma unroll
      for (int ni = 0; ni < 8; ++ni) {
        s8v bk = *(const s8v*)&Ks[(ni * 16 + llo) * ALD + ks * 32 + g * 8];
        sc[ni] = __builtin_amdgcn_mfma_f32_16x16x32_bf16(qreg[ks], bk, sc[ni], 0, 0, 0);
      }
    }

    const bool diag = (kt == qt);
#pragma unroll
    for (int r = 0; r < 4; ++r) {
      int rowl = w * 16 + g * 4 + r;   // row within 128-tile
      float mx = -1e30f;
#pragma unroll
      for (int ni = 0; ni < 8; ++ni) {
        float v = sc[ni][r] * scale;
        if (diag && (ni * 16 + llo) > rowl) v = -1e30f;
        sc[ni][r] = v;
        mx = fmaxf(mx, v);
      }
      mx = fmaxf(mx, __shfl_xor(mx, 1, 64));
      mx = fmaxf(mx, __shfl_xor(mx, 2, 64));
      mx = fmaxf(mx, __shfl_xor(mx, 4, 64));
      mx = fmaxf(mx, __shfl_xor(mx, 8, 64));
      float mnew  = fmaxf(m_i[r], mx);
      float alpha = __expf(m_i[r] - mnew);
      m_i[r] = mnew;
      float rs = 0.f;
#pragma unroll
      for (int ni = 0; ni < 8; ++ni) {
        float p = __expf(sc[ni][r] - mnew);
        rs += p;
        Ps[rowl * ALD + ni * 16 + llo] = f2b(p);
      }
      rs += __shfl_xor(rs, 1, 64);
      rs += __shfl_xor(rs, 2, 64);
      rs += __shfl_xor(rs, 4, 64);
      rs += __shfl_xor(rs, 8, 64);
      l_i[r] = l_i[r] * alpha + rs;
#pragma unroll
      for (int ni = 0; ni < 8; ++ni) o[ni][r] *= alpha;
    }
    // Ps strip is wave-private: lgkmcnt ordering suffices, no barrier

    // O += P V
#pragma unroll
    for (int ks = 0; ks < 4; ++ks) {
      s8v ap = *(const s8v*)&Ps[(w * 16 + llo) * ALD + ks * 32 + g * 8];
#pragma unroll
      for (int ni = 0; ni < 8; ++ni) {
        s8v bv = *(const s8v*)&Vt[(ni * 16 + llo) * ALD + ks * 32 + g * 8];
        o[ni] = __builtin_amdgcn_mfma_f32_16x16x32_bf16(ap, bv, o[ni], 0, 0, 0);
      }
    }
  }

#pragma unroll
  for (int r = 0; r < 4; ++r) {
    float inv = 1.f / l_i[r];
    size_t obase = (size_t)(b * 1024 + qt * 128 + w * 16 + g * 4 + r) * 1024 + hh * 128;
#pragma unroll
    for (int ni = 0; ni < 8; ++ni)
      att[obase + ni * 16 + llo] = f2b(o[ni][r] * inv);
  }
}

// ---------------------------------------------------------------------------
// LayerNorm over D=1024: in f32 -> outf f32 (optional, may alias in) + outb bf16
// ---------------------------------------------------------------------------
__global__ __launch_bounds__(256)
void ln_kernel(const float* in, const float* __restrict__ gw,
               const float* __restrict__ bw, float* outf,
               short* __restrict__ outb) {
  const int row = blockIdx.x, tid = threadIdx.x;
  const int lane = tid & 63, w = tid >> 6;
  float4 v = *(const float4*)(in + (size_t)row * 1024 + tid * 4);
  float s = v.x + v.y + v.z + v.w;
  float q = v.x * v.x + v.y * v.y + v.z * v.z + v.w * v.w;
  for (int off = 1; off < 64; off <<= 1) {
    s += __shfl_xor(s, off, 64);
    q += __shfl_xor(q, off, 64);
  }
  __shared__ float red[8];
  if (lane == 0) { red[w] = s; red[4 + w] = q; }
  __syncthreads();
  s = red[0] + red[1] + red[2] + red[3];
  q = red[4] + red[5] + red[6] + red[7];
  const float mean = s * (1.0f / 1024.0f);
  const float var  = q * (1.0f / 1024.0f) - mean * mean;
  const float rstd = rsqrtf(var + 1e-5f);
  const int d = tid * 4;
  float4 gv = *(const float4*)(gw + d);
  float4 bv = *(const float4*)(bw + d);
  float o0 = (v.x - mean) * rstd * gv.x + bv.x;
  float o1 = (v.y - mean) * rstd * gv.y + bv.y;
  float o2 = (v.z - mean) * rstd * gv.z + bv.z;
  float o3 = (v.w - mean) * rstd * gv.w + bv.w;
  if (outf) {
    float4 ov = {o0, o1, o2, o3};
    *(float4*)(outf + (size_t)row * 1024 + d) = ov;
  }
  s4v ob = {f2b(o0), f2b(o1), f2b(o2), f2b(o3)};
  *(s4v*)(outb + (size_t)row * 1024 + d) = ob;
}

// ---------------------------------------------------------------------------
// Patch embedding: h[m,d] = sum_p x[m*96+p] * Wemb[d,p] + PE(m%1024, d)
// ---------------------------------------------------------------------------
__global__ __launch_bounds__(256)
void embed_kernel(const float* __restrict__ x, const short* __restrict__ Wemb,
                  float* __restrict__ hf, short* __restrict__ hb) {
  __shared__ float Xs[16 * 96];
  const int tid = threadIdx.x;
  const int m0  = blockIdx.x * 16;
  for (int i = tid; i < 16 * 96; i += 256) Xs[i] = x[(size_t)m0 * 96 + i];
  __syncthreads();

  const int d0 = tid * 4;
  float acc[4][16];
#pragma unroll
  for (int j = 0; j < 4; ++j)
#pragma unroll
    for (int t = 0; t < 16; ++t) acc[j][t] = 0.f;

  for (int pc = 0; pc < 12; ++pc) {
    float wf[4][8];
#pragma unroll
    for (int j = 0; j < 4; ++j) {
      s8v wv = *(const s8v*)&Wemb[(size_t)(d0 + j) * 96 + pc * 8];
#pragma unroll
      for (int u = 0; u < 8; ++u) wf[j][u] = b2f(wv[u]);
    }
#pragma unroll
    for (int t = 0; t < 16; ++t) {
      float4 xa = *(const float4*)&Xs[t * 96 + pc * 8];
      float4 xb = *(const float4*)&Xs[t * 96 + pc * 8 + 4];
      float xv[8] = {xa.x, xa.y, xa.z, xa.w, xb.x, xb.y, xb.z, xb.w};
#pragma unroll
      for (int u = 0; u < 8; ++u)
#pragma unroll
        for (int j = 0; j < 4; ++j) acc[j][t] += xv[u] * wf[j][u];
    }
  }

#pragma unroll
  for (int j = 0; j < 4; ++j) {
    int d = d0 + j;
    float freq = __expf((float)(d & ~1) * (-0.008994473019508041f)); // -ln(1e4)/1024
#pragma unroll
    for (int t = 0; t < 16; ++t) {
      int n = (m0 + t) & 1023;
      float arg = (float)n * freq;
      float pe  = (d & 1) ? cosf(arg) : sinf(arg);
      float val = acc[j][t] + pe;
      hf[(size_t)(m0 + t) * 1024 + d] = val;
      hb[(size_t)(m0 + t) * 1024 + d] = f2b(val);
    }
  }
}

// ---------------------------------------------------------------------------
extern "C" void kernel_launch(void* const* d_in, const int* in_sizes, int n_in,
                              void* d_out, int out_size, void* d_ws, size_t ws_size,
                              hipStream_t stream) {
  (void)in_sizes; (void)n_in; (void)out_size; (void)ws_size;
  const float* x    = (const float*)d_in[0];
  const float* Wemb = (const float*)d_in[1];
  const float* Wq   = (const float*)d_in[2];
  const float* bq   = (const float*)d_in[3];
  const float* Wk   = (const float*)d_in[4];
  const float* bk   = (const float*)d_in[5];
  const float* Wv   = (const float*)d_in[6];
  const float* bv   = (const float*)d_in[7];
  const float* Wo   = (const float*)d_in[8];
  const float* bo   = (const float*)d_in[9];
  const float* Wc1  = (const float*)d_in[10];
  const float* bc1  = (const float*)d_in[11];
  const float* Wc2  = (const float*)d_in[12];
  const float* bc2  = (const float*)d_in[13];
  const float* g1   = (const float*)d_in[14];
  const float* be1  = (const float*)d_in[15];
  const float* g2   = (const float*)d_in[16];
  const float* be2  = (const float*)d_in[17];
  const float* gN   = (const float*)d_in[18];
  const float* beN  = (const float*)d_in[19];
  const float* Wp   = (const float*)d_in[20];
  const float* bp   = (const float*)d_in[21];

  char* wsc = (char*)d_ws;
  const size_t MB = 1024 * 1024;
  short* wqkv_b = (short*)(wsc + 0 * MB);      // 48 MB  [8][3072][1024] bf16
  short* wo_b   = (short*)(wsc + 48 * MB);     // 16 MB
  short* wc1_b  = (short*)(wsc + 64 * MB);     // 32 MB
  short* wc2_b  = (short*)(wsc + 96 * MB);     // 32 MB
  short* wemb_b = (short*)(wsc + 128 * MB);                 // 192 KB
  short* wp_b   = (short*)(wsc + 128 * MB + 196608);        // 192 KB
  float* bqkv   = (float*)(wsc + 128 * MB + 393216);        //  96 KB [8][3072] f32
  float* h_f32  = (float*)(wsc + 129 * MB);    // 16 MB fp32 residual trunk
  short* h_bf   = (short*)(wsc + 145 * MB);    //  8 MB bf16 A-operand copy
  short* qkv    = (short*)(wsc + 153 * MB);    // 24 MB [4096,3072]; aliased as y1
  short* att    = (short*)(wsc + 177 * MB);    //  8 MB [4096,1024]
  short* y1     = qkv;                         // FFN mid [4096,2048]

  // weight prep: fp32 -> bf16 (+ QKV fusion)
  cvt_pack_w<<<8192, 256, 0, stream>>>(Wq, wqkv_b, 0);
  cvt_pack_w<<<8192, 256, 0, stream>>>(Wk, wqkv_b, 1024);
  cvt_pack_w<<<8192, 256, 0, stream>>>(Wv, wqkv_b, 2048);
  pack_bias<<<32, 256, 0, stream>>>(bq, bqkv, 0);
  pack_bias<<<32, 256, 0, stream>>>(bk, bqkv, 1024);
  pack_bias<<<32, 256, 0, stream>>>(bv, bqkv, 2048);
  cvt_f32_bf16<<<8192, 256, 0, stream>>>(Wo, wo_b, 8 * 1024 * 1024);
  cvt_f32_bf16<<<16384, 256, 0, stream>>>(Wc1, wc1_b, 16 * 1024 * 1024);
  cvt_f32_bf16<<<16384, 256, 0, stream>>>(Wc2, wc2_b, 16 * 1024 * 1024);
  cvt_f32_bf16<<<96, 256, 0, stream>>>(Wemb, wemb_b, 98304);
  cvt_f32_bf16<<<96, 256, 0, stream>>>(Wp, wp_b, 98304);

  embed_kernel<<<256, 256, 0, stream>>>(x, wemb_b, h_f32, h_bf);

  for (int i = 0; i < 8; ++i) {
    const short* wqkv = wqkv_b + (size_t)i * 3072 * 1024;
    const short* wo = wo_b + (size_t)i * 1024 * 1024;
    const short* w1 = wc1_b + (size_t)i * 2048 * 1024;
    const short* w2 = wc2_b + (size_t)i * 1024 * 2048;

    // fused QKV: [4096,3072], 768 blocks (3/CU)
    gemm_bt<<<dim3(32, 24), 256, 0, stream>>>(h_bf, wqkv, bqkv + i * 3072, nullptr,
                                              nullptr, qkv, 4096, 3072, 1024, 3072, 0);
    attn_kernel<<<dim3(8, 8, 4), 512, 0, stream>>>(qkv, att);
    // h += att @ Wo^T + bo   (in-place residual, 512 blocks)
    gemm_bt64<<<dim3(64, 8), 256, 0, stream>>>(att, wo, bo + i * 1024, h_f32,
                                               h_f32, nullptr, 4096, 1024, 1024, 1024, 0);
    ln_kernel<<<4096, 256, 0, stream>>>(h_f32, g1 + i * 1024, be1 + i * 1024, h_f32, h_bf);
    gemm_bt<<<dim3(32, 16), 256, 0, stream>>>(h_bf, w1, bc1 + i * 2048, nullptr,
                                              nullptr, y1, 4096, 2048, 1024, 2048, 1);
    gemm_bt64<<<dim3(64, 8), 256, 0, stream>>>(y1, w2, bc2 + i * 1024, h_f32,
                                               h_f32, nullptr, 4096, 1024, 2048, 1024, 0);
    ln_kernel<<<4096, 256, 0, stream>>>(h_f32, g2 + i * 1024, be2 + i * 1024, h_f32, h_bf);
  }

  ln_kernel<<<4096, 256, 0, stream>>>(h_f32, gN, beN, nullptr, h_bf);
  gemm_bt64<<<dim3(64, 1), 256, 0, stream>>>(h_bf, wp_b, bp, nullptr,
                                             (float*)d_out, nullptr, 4096, 96, 1024, 96, 0);
}